// Round 5
// baseline (159.643 us; speedup 1.0000x reference)
//
#include <hip/hip_runtime.h>
#include <math.h>

// loss = ALPHA * mean(level_w * (softplus(x) - x*t))
//      + BETA  * sum_{b,e} relu(sig(x[b,dst]) - sig(x[b,src])) / (B*N)
// (scatter target of the consistency add is irrelevant to the mean)
//
// R4: R=8 rows/block, p stored TRANSPOSED IN FP16: p_lds[n] = half8 of rows
// r0..r0+7, so ONE ds_read_b128 serves 8 edge-instances (2x the float4
// scheme). Packed-fp16 VALU (v_pk_*) for the edge math. 64 KB LDS,
// 1024 threads, 2 blocks/CU = 32 waves/CU. launch_bounds caps VGPR at 64.

#define ALPHA_C 1.0f
#define BETA_C  0.5f

constexpr int B = 4096;
constexpr int N = 4096;
constexpr int E = 16384;
constexpr int THREADS = 1024;
constexpr int R = 8;            // rows per block

typedef _Float16 h8 __attribute__((ext_vector_type(8)));

__global__ __launch_bounds__(64) void init_out_kernel(float* out) {
    if (threadIdx.x == 0) out[0] = 0.0f;
}

__device__ __forceinline__ void fast_sig_sp(float x, float& p, float& sp) {
    // q = exp(-|x|) in (0,1]; both sigmoid and softplus from one exp
    float q = __expf(-fabsf(x));
    float d = 1.0f + q;
    float r = __builtin_amdgcn_rcpf(d);     // ~1 ulp approx reciprocal
    p  = (x >= 0.0f) ? r : q * r;           // sigmoid
    sp = fmaxf(x, 0.0f) + __logf(d);        // softplus = max(x,0)+log(1+q)
}

__global__ __launch_bounds__(THREADS, 8) void hier_loss_kernel(
    const float* __restrict__ outputs,
    const float* __restrict__ targets,
    const float* __restrict__ level_w,
    const int*   __restrict__ edge_src,
    const int*   __restrict__ edge_dst,
    float*       __restrict__ out)
{
    __shared__ h8 P[N];             // 64 KB: P[n] = fp16 p of rows r0..r0+7

    const int r0  = blockIdx.x * R;
    const int tid = threadIdx.x;

    const float4* out4 = (const float4*)outputs;
    const float4* tgt4 = (const float4*)targets;
    const float4* lw4  = (const float4*)level_w;

    // ---- phase 1: BCE sum + fp16 transposed sigmoid into LDS ----
    // thread owns n = 4*tid .. 4*tid+3 (one float4 per row), all 8 rows.
    float s1 = 0.0f;
    {
        const float4 w = lw4[tid];
        const float wv[4] = {w.x, w.y, w.z, w.w};
        h8 tmp[4];                  // tmp[k][r] = p(row r, n=4*tid+k)
#pragma unroll
        for (int r = 0; r < R; ++r) {
            const int row = r0 + r;
            const float4 x = out4[(size_t)row * (N / 4) + tid];
            const float4 t = tgt4[(size_t)row * (N / 4) + tid];
            const float xs[4] = {x.x, x.y, x.z, x.w};
            const float ts[4] = {t.x, t.y, t.z, t.w};
#pragma unroll
            for (int k = 0; k < 4; ++k) {
                float p, sp;
                fast_sig_sp(xs[k], p, sp);
                s1 = fmaf(wv[k], sp - xs[k] * ts[k], s1);
                tmp[k][r] = (_Float16)p;
            }
        }
#pragma unroll
        for (int k = 0; k < 4; ++k) P[4 * tid + k] = tmp[k];
    }
    __syncthreads();

    // ---- phase 2: edge consistency; one b128 gather covers 8 rows ----
    h8 acc0 = {0, 0, 0, 0, 0, 0, 0, 0};
    h8 acc1 = {0, 0, 0, 0, 0, 0, 0, 0};
    const h8 zero = {0, 0, 0, 0, 0, 0, 0, 0};
    const int4* es4 = (const int4*)edge_src;
    const int4* ed4 = (const int4*)edge_dst;
#pragma unroll
    for (int j = 0; j < E / 4 / THREADS; ++j) {      // 4 iters
        const int i = tid + j * THREADS;
        const int4 s = es4[i];
        const int4 d = ed4[i];
        h8 a0 = P[s.x], c0 = P[d.x];
        h8 a1 = P[s.y], c1 = P[d.y];
        h8 a2 = P[s.z], c2 = P[d.z];
        h8 a3 = P[s.w], c3 = P[d.w];
        acc0 += __builtin_elementwise_max(c0 - a0, zero);   // v_pk_max_f16
        acc1 += __builtin_elementwise_max(c1 - a1, zero);
        acc0 += __builtin_elementwise_max(c2 - a2, zero);
        acc1 += __builtin_elementwise_max(c3 - a3, zero);
    }
    float s2 = 0.0f;
#pragma unroll
    for (int l = 0; l < 8; ++l) s2 += (float)acc0[l] + (float)acc1[l];

    // ---- block reduce: wave64 shuffle, cross-wave via reused LDS ----
#pragma unroll
    for (int off = 32; off > 0; off >>= 1) {
        s1 += __shfl_down(s1, off, 64);
        s2 += __shfl_down(s2, off, 64);
    }
    __syncthreads();                     // all phase-2 reads done before reuse
    float* red = (float*)P;
    const int wave = tid >> 6;           // 16 waves
    const int lane = tid & 63;
    if (lane == 0) { red[wave] = s1; red[16 + wave] = s2; }
    __syncthreads();
    if (tid == 0) {
        float a = 0.0f, c = 0.0f;
#pragma unroll
        for (int w = 0; w < 16; ++w) { a += red[w]; c += red[16 + w]; }
        const float inv = 1.0f / ((float)B * (float)N);
        atomicAdd(out, (ALPHA_C * a + BETA_C * c) * inv);
    }
}

extern "C" void kernel_launch(void* const* d_in, const int* in_sizes, int n_in,
                              void* d_out, int out_size, void* d_ws, size_t ws_size,
                              hipStream_t stream) {
    const float* outputs = (const float*)d_in[0];
    const float* targets = (const float*)d_in[1];
    const float* level_w = (const float*)d_in[2];
    const int*   edge_src = (const int*)d_in[3];
    const int*   edge_dst = (const int*)d_in[4];
    float* out = (float*)d_out;

    init_out_kernel<<<1, 64, 0, stream>>>(out);
    hier_loss_kernel<<<B / R, THREADS, 0, stream>>>(outputs, targets, level_w,
                                                    edge_src, edge_dst, out);
}

// Round 6
// 156.640 us; speedup vs baseline: 1.0192x; 1.0192x over previous
//
#include <hip/hip_runtime.h>
#include <math.h>

// loss = ALPHA * mean(level_w * (softplus(x) - x*t))
//      + BETA  * sum_{b,e} relu(sig(x[b,dst]) - sig(x[b,src])) / (B*N)
// (scatter target of the consistency add is irrelevant to the mean)
//
// R5: R=4 rows/block in fp16 (half4 -> 32 KB LDS), 512-thread blocks,
// grid=1024 -> 4 blocks/CU co-resident. Staggered blocks overlap phase-1
// (global mem + transcendentals) with phase-2 (LDS gathers), and each
// barrier stalls only 8 waves. Phase-1 batches all 8 loads per column
// before math so VMEM latency is covered by in-flight loads.

#define ALPHA_C 1.0f
#define BETA_C  0.5f

constexpr int B = 4096;
constexpr int N = 4096;
constexpr int E = 16384;
constexpr int THREADS = 512;
constexpr int R = 4;            // rows per block

typedef _Float16 h4 __attribute__((ext_vector_type(4)));

__global__ __launch_bounds__(64) void init_out_kernel(float* out) {
    if (threadIdx.x == 0) out[0] = 0.0f;
}

__device__ __forceinline__ void fast_sig_sp(float x, float& p, float& sp) {
    // q = exp(-|x|) in (0,1]; both sigmoid and softplus from one exp
    float q = __expf(-fabsf(x));
    float d = 1.0f + q;
    float r = __builtin_amdgcn_rcpf(d);     // ~1 ulp approx reciprocal
    p  = (x >= 0.0f) ? r : q * r;           // sigmoid
    sp = fmaxf(x, 0.0f) + __logf(d);        // softplus = max(x,0)+log(1+q)
}

__global__ __launch_bounds__(THREADS, 8) void hier_loss_kernel(
    const float* __restrict__ outputs,
    const float* __restrict__ targets,
    const float* __restrict__ level_w,
    const int*   __restrict__ edge_src,
    const int*   __restrict__ edge_dst,
    float*       __restrict__ out)
{
    __shared__ h4 P[N];             // 32 KB: P[n] = fp16 p of rows r0..r0+3

    const int r0  = blockIdx.x * R;
    const int tid = threadIdx.x;

    const float4* out4 = (const float4*)outputs;
    const float4* tgt4 = (const float4*)targets;
    const float4* lw4  = (const float4*)level_w;

    // ---- phase 1: BCE sum + fp16 transposed sigmoid into LDS ----
    float s1 = 0.0f;
#pragma unroll
    for (int j = 0; j < N / 4 / THREADS; ++j) {      // 2 iters
        const int n4 = tid + j * THREADS;            // float4-column index
        const float4 w = lw4[n4];
        const float wv[4] = {w.x, w.y, w.z, w.w};
        // batch ALL loads for this column group first (8 in flight)
        float4 xs[R], ts[R];
#pragma unroll
        for (int r = 0; r < R; ++r) {
            xs[r] = out4[(size_t)(r0 + r) * (N / 4) + n4];   // coalesced
            ts[r] = tgt4[(size_t)(r0 + r) * (N / 4) + n4];
        }
        h4 tmp[4];                  // tmp[k][r] = p(row r0+r, node 4*n4+k)
#pragma unroll
        for (int r = 0; r < R; ++r) {
            const float xv[4] = {xs[r].x, xs[r].y, xs[r].z, xs[r].w};
            const float tv[4] = {ts[r].x, ts[r].y, ts[r].z, ts[r].w};
#pragma unroll
            for (int k = 0; k < 4; ++k) {
                float p, sp;
                fast_sig_sp(xv[k], p, sp);
                s1 = fmaf(wv[k], sp - xv[k] * tv[k], s1);
                tmp[k][r] = (_Float16)p;
            }
        }
#pragma unroll
        for (int k = 0; k < 4; ++k) P[4 * n4 + k] = tmp[k]; // 2x ds_write_b128
    }
    __syncthreads();

    // ---- phase 2: edge consistency; one b64 gather covers 4 rows ----
    h4 acc0 = {0, 0, 0, 0};
    h4 acc1 = {0, 0, 0, 0};
    const h4 zero = {0, 0, 0, 0};
    const int4* es4 = (const int4*)edge_src;
    const int4* ed4 = (const int4*)edge_dst;
#pragma unroll
    for (int j = 0; j < E / 4 / THREADS; ++j) {      // 8 iters
        const int i = tid + j * THREADS;
        const int4 s = es4[i];
        const int4 d = ed4[i];
        h4 a0 = P[s.x], c0 = P[d.x];
        h4 a1 = P[s.y], c1 = P[d.y];
        h4 a2 = P[s.z], c2 = P[d.z];
        h4 a3 = P[s.w], c3 = P[d.w];
        acc0 += __builtin_elementwise_max(c0 - a0, zero);   // v_pk_* fp16
        acc1 += __builtin_elementwise_max(c1 - a1, zero);
        acc0 += __builtin_elementwise_max(c2 - a2, zero);
        acc1 += __builtin_elementwise_max(c3 - a3, zero);
    }
    float s2 = 0.0f;
#pragma unroll
    for (int l = 0; l < 4; ++l) s2 += (float)acc0[l] + (float)acc1[l];

    // ---- block reduce: wave64 shuffle, cross-wave via reused LDS ----
#pragma unroll
    for (int off = 32; off > 0; off >>= 1) {
        s1 += __shfl_down(s1, off, 64);
        s2 += __shfl_down(s2, off, 64);
    }
    __syncthreads();                     // all phase-2 reads done before reuse
    float* red = (float*)P;
    const int wave = tid >> 6;           // 8 waves
    const int lane = tid & 63;
    if (lane == 0) { red[wave] = s1; red[8 + wave] = s2; }
    __syncthreads();
    if (tid == 0) {
        float a = 0.0f, c = 0.0f;
#pragma unroll
        for (int w = 0; w < 8; ++w) { a += red[w]; c += red[8 + w]; }
        const float inv = 1.0f / ((float)B * (float)N);
        atomicAdd(out, (ALPHA_C * a + BETA_C * c) * inv);
    }
}

extern "C" void kernel_launch(void* const* d_in, const int* in_sizes, int n_in,
                              void* d_out, int out_size, void* d_ws, size_t ws_size,
                              hipStream_t stream) {
    const float* outputs = (const float*)d_in[0];
    const float* targets = (const float*)d_in[1];
    const float* level_w = (const float*)d_in[2];
    const int*   edge_src = (const int*)d_in[3];
    const int*   edge_dst = (const int*)d_in[4];
    float* out = (float*)d_out;

    init_out_kernel<<<1, 64, 0, stream>>>(out);
    hier_loss_kernel<<<B / R, THREADS, 0, stream>>>(outputs, targets, level_w,
                                                    edge_src, edge_dst, out);
}